// Round 10
// baseline (583.254 us; speedup 1.0000x reference)
//
#include <hip/hip_runtime.h>
#include <hip/hip_bf16.h>
#include <math.h>

typedef unsigned short u16;
typedef __attribute__((ext_vector_type(8))) short s16x8;
typedef __attribute__((ext_vector_type(4))) float f32x4;
typedef __attribute__((ext_vector_type(16))) float f32x16;
typedef __attribute__((ext_vector_type(4))) unsigned short u16x4;

__device__ __forceinline__ u16 f2bf(float f) {
  union { float f; unsigned u; } v; v.f = f;
  unsigned r = (v.u + 0x7FFFu + ((v.u >> 16) & 1u)) >> 16;
  return (u16)r;
}

__device__ __forceinline__ void gload16(const void* g, void* l) {
  __builtin_amdgcn_global_load_lds((const __attribute__((address_space(1))) unsigned int*)g,
                                   (__attribute__((address_space(3))) unsigned int*)l, 16, 0, 0);
}

__device__ __forceinline__ unsigned cvt_pk_bf16(float a, float b) {
  unsigned r;
  asm("v_cvt_pk_bf16_f32 %0, %1, %2" : "=v"(r) : "v"(a), "v"(b));
  return r;
}

// ---------------- elementwise prep ----------------

__global__ __launch_bounds__(256) void cvt_weights(
    const float* __restrict__ wq, const float* __restrict__ wk, const float* __restrict__ wv,
    const float* __restrict__ wo, const float* __restrict__ wf,
    u16* __restrict__ wqkv, u16* __restrict__ wobf, u16* __restrict__ wfbf)
{
  int i = blockIdx.x * 256 + threadIdx.x;   // 5 * 262144 float4 units
  int which = i >> 18;
  int idx = i & 262143;
  const float* src = which==0 ? wq : which==1 ? wk : which==2 ? wv : which==3 ? wo : wf;
  float4 v = ((const float4*)src)[idx];
  u16x4 o = { f2bf(v.x), f2bf(v.y), f2bf(v.z), f2bf(v.w) };
  u16* dst = which < 3 ? (wqkv + (size_t)which*1048576) : (which==3 ? wobf : wfbf);
  ((u16x4*)dst)[idx] = o;
}

// M[b*1664 + s] = rows of [x(1024); h_a(64); p(64); h_t(512)] per batch, bf16
__global__ __launch_bounds__(256) void build_m(
    const float* __restrict__ x, const float* __restrict__ ht,
    const float* __restrict__ ha, const float* __restrict__ p,
    u16* __restrict__ M)
{
  int row = blockIdx.x; int t = threadIdx.x;
  int b = row / 1664, s = row % 1664;
  const float* src;
  if (s < 1024)      src = x  + (size_t)(b*1024 + s)*1024;
  else if (s < 1088) src = ha + (size_t)(b*64 + (s-1024))*1024;
  else if (s < 1152) src = p  + (size_t)(b*64 + (s-1088))*1024;
  else               src = ht + (size_t)(b*512 + (s-1152))*1024;
  float4 v = ((const float4*)src)[t];
  u16x4 o = { f2bf(v.x), f2bf(v.y), f2bf(v.z), f2bf(v.w) };
  ((u16x4*)(M + (size_t)row*1024))[t] = o;
}

// ---------------- unified 128x128 GEMM, K=1024, BK=32, double-buffered ----------------
// LDS = 32 KB -> 5 blocks/CU (__launch_bounds__(256,5)); depth-1 prefetch,
// one fused {vmcnt(0), s_barrier} per K-iter; cross-block TLP hides the drain.
// EPI 0: fused QKV epilogue. EPI 1: +bias+resid -> fp32. EPI 2: +bias+relu -> fp32.

template<int EPI>
__global__ __launch_bounds__(256, 5) void gemm128(
    const u16* __restrict__ A, const u16* __restrict__ Bw,
    const float* __restrict__ bias0, const float* __restrict__ bias1,
    const float* __restrict__ bias2, const float* __restrict__ gat,
    void* o0, void* o1, void* o2, const float* __restrict__ resid,
    int mpx, int ng)
{
  __shared__ __align__(16) u16 As2[2][128*32];   // 8 KB per buf per matrix
  __shared__ __align__(16) u16 Bs2[2][128*32];   // total 32 KB

  const int tid = threadIdx.x;
  const int l = tid & 63;
  const int w = tid >> 6;            // 0..3
  const int wr = w >> 1, wc = w & 1; // 2x2 wave grid, 64x64 per wave
  const int l15 = l & 15, lg = l >> 4;

  // XCD-chunked swizzle: each XCD owns mpx contiguous mt x nt-groups of ng.
  const int b0 = blockIdx.x;
  const int xcd = b0 & 7;
  const int loc = b0 >> 3;
  const int chunk = mpx * ng;
  const int g = loc / chunk, r5 = loc % chunk;
  const int mt = xcd*mpx + (r5 % mpx);
  const int nt = g*ng + (r5 / mpx);
  const int m0 = mt * 128, n0 = nt * 128;

  if constexpr (EPI == 0) {
    if (n0 < 1024 && (m0 % 1664) >= 1024) return;  // Q-only tile, all non-token rows
  }

  // stage K-tile kt into buffer sb; chunk-XOR c^=(r>>1)&3 via pre-swizzled global src.
  auto stage = [&](int kt, int sb) {
    #pragma unroll
    for (int i=0;i<2;++i) {
      const int e = i*256 + tid;
      const int rr = e >> 2, c2 = e & 3;
      const int gch = c2 ^ ((rr >> 1) & 3);
      gload16(A + (size_t)(m0 + rr)*1024 + kt*32 + gch*8,
              (void*)(As2[sb] + (i*256 + w*64)*8));
    }
    #pragma unroll
    for (int i=0;i<2;++i) {
      const int e = i*256 + tid;
      const int rr = e >> 2, c2 = e & 3;
      const int gch = c2 ^ ((rr >> 1) & 3);
      gload16(Bw + (size_t)(n0 + rr)*1024 + kt*32 + gch*8,
              (void*)(Bs2[sb] + (i*256 + w*64)*8));
    }
  };

  f32x4 acc[4][4];
  #pragma unroll
  for (int i=0;i<4;++i)
    #pragma unroll
    for (int j=0;j<4;++j) acc[i][j] = (f32x4){0,0,0,0};

  stage(0, 0);
  asm volatile("s_waitcnt vmcnt(0)\ns_barrier" ::: "memory");

  for (int t = 0; t < 32; ++t) {
    const int cur = t & 1;
    if (t + 1 < 32) stage(t + 1, cur ^ 1);

    s16x8 af[4], bf[4];
    #pragma unroll
    for (int mi=0;mi<4;++mi) {
      const int rr = wr*64 + mi*16 + l15;
      af[mi] = *(const s16x8*)(As2[cur] + rr*32 + ((lg ^ ((rr>>1)&3))<<3));
    }
    #pragma unroll
    for (int ni=0;ni<4;++ni) {
      const int rr = wc*64 + ni*16 + l15;
      bf[ni] = *(const s16x8*)(Bs2[cur] + rr*32 + ((lg ^ ((rr>>1)&3))<<3));
    }

    __builtin_amdgcn_s_setprio(1);
    #pragma unroll
    for (int mi=0;mi<4;++mi)
      #pragma unroll
      for (int ni=0;ni<4;++ni)
        acc[mi][ni] = __builtin_amdgcn_mfma_f32_16x16x32_bf16(af[mi], bf[ni], acc[mi][ni], 0,0,0);
    __builtin_amdgcn_s_setprio(0);

    if (t < 31) asm volatile("s_waitcnt vmcnt(0)\ns_barrier" ::: "memory");
  }

  // epilogue
  float ratio = 0.f;
  if constexpr (EPI == 0) ratio = tanhf(gat[0]);

  #pragma unroll
  for (int mi=0;mi<4;++mi) {
    #pragma unroll
    for (int ni=0;ni<4;++ni) {
      #pragma unroll
      for (int rr=0;rr<4;++rr) {
        const int row = m0 + wr*64 + mi*16 + lg*4 + rr;
        const int col = n0 + wc*64 + ni*16 + l15;
        const float a = acc[mi][ni][rr];
        if constexpr (EPI == 0) {
          const int b = row / 1664, s = row % 1664;
          if (col < 1024) {
            if (s < 1024) {
              float v = a + bias0[col];
              ((u16*)o0)[(size_t)(b*1024 + s)*1024 + col] = f2bf(v * 0.08838834764831845f);
            }
          } else if (col < 2048) {
            float v = a + bias1[col-1024];
            if (s >= 1152) v *= ratio;
            ((u16*)o1)[(size_t)row*1024 + (col-1024)] = f2bf(v);
          } else {
            float v = a + bias2[col-2048];
            ((u16*)o2)[(size_t)row*1024 + (col-2048)] = f2bf(v);
          }
        } else if constexpr (EPI == 1) {
          float v = a + bias0[col] + resid[(size_t)row*1024 + col];
          ((float*)o0)[(size_t)row*1024 + col] = v;
        } else {
          float v = a + bias0[col];
          ((float*)o0)[(size_t)row*1024 + col] = fmaxf(v, 0.f);
        }
      }
    }
  }
}

// ---------------- V transpose: Vt[b][c=1024][s=1664] = V[b][s][c] ----------------

__global__ __launch_bounds__(256) void vtrans(
    const u16* __restrict__ V, u16* __restrict__ Vt)
{
  __shared__ u16 Ls[64][68];
  const int st = blockIdx.x, dt = blockIdx.y, b = blockIdx.z;
  const int t = threadIdx.x;
  const int rq = t >> 4, c4 = t & 15;
  #pragma unroll
  for (int i=0;i<4;++i) {
    const int r = i*16 + rq;
    u16x4 v = *(const u16x4*)(V + ((size_t)(b*1664 + st*64 + r))*1024 + dt*64 + c4*4);
    Ls[r][c4*4+0] = v[0]; Ls[r][c4*4+1] = v[1]; Ls[r][c4*4+2] = v[2]; Ls[r][c4*4+3] = v[3];
  }
  __syncthreads();
  #pragma unroll
  for (int i=0;i<4;++i) {
    const int dr = i*16 + rq;
    u16x4 ov = { Ls[c4*4+0][dr], Ls[c4*4+1][dr], Ls[c4*4+2][dr], Ls[c4*4+3][dr] };
    *(u16x4*)(Vt + ((size_t)(b*1024 + dt*64 + dr))*1664 + st*64 + c4*4) = ov;
  }
}

// ---------------- flash attention, 32x32 swapped-QK, S=1664, D=128 ----------------

__global__ __launch_bounds__(256, 2) void flash_attn(
    const u16* __restrict__ Q, const u16* __restrict__ Kb, const u16* __restrict__ Vtg,
    u16* __restrict__ O)
{
  __shared__ __align__(16) u16 Kl[2][64*128];   // [s][16 chunks], chunk low3 ^= s&7
  __shared__ __align__(16) u16 Vl[2][128*64];   // [d][8 chunks], chunk ^= d&7

  const int tid = threadIdx.x;
  const int l = tid & 63;
  const int w = tid >> 6;
  const int l31 = l & 31;
  const int hi = l >> 5;
  const int bh = blockIdx.x & 63;
  const int qt = blockIdx.x >> 6;
  const int b = bh >> 3, h = bh & 7;
  const int colh = h * 128;
  const int q0 = qt*128 + w*32;

  s16x8 qf[8];
  {
    const size_t qrow = (size_t)(b*1024 + q0 + l31)*1024 + colh;
    #pragma unroll
    for (int kc=0;kc<8;++kc)
      qf[kc] = *(const s16x8*)(Q + qrow + kc*16 + hi*8);
  }

  f32x16 oacc[4];
  #pragma unroll
  for (int dt2=0;dt2<4;++dt2)
    #pragma unroll
    for (int i=0;i<16;++i) oacc[dt2][i] = 0.f;
  float m_run = -INFINITY, l_run = 0.f;

  const size_t kbase  = (size_t)(b*1664)*1024 + colh;
  const size_t vtbase = (size_t)(b*1024 + colh)*1664;

  auto stage = [&](int st, int nb) {
    const int s0 = st*64;
    #pragma unroll
    for (int i=0;i<4;++i) {
      const int e = i*256 + tid;
      const int sl = e >> 4, c = e & 15;
      const int g = (c & 8) | ((c ^ sl) & 7);
      gload16(Kb + kbase + (size_t)(s0 + sl)*1024 + g*8,
              (void*)(Kl[nb] + (i*256 + w*64)*8));
    }
    #pragma unroll
    for (int i=0;i<4;++i) {
      const int e = i*256 + tid;
      const int d = e >> 3, c3 = e & 7;
      const int g3 = (c3 ^ d) & 7;
      gload16(Vtg + vtbase + (size_t)d*1664 + s0 + g3*8,
              (void*)(Vl[nb] + (i*256 + w*64)*8));
    }
  };

  stage(0, 0);
  __syncthreads();
  int cur = 0;

  for (int st=0; st<26; ++st) {
    if (st + 1 < 26) stage(st + 1, cur ^ 1);

    f32x16 sacc[2];
    #pragma unroll
    for (int stile=0; stile<2; ++stile) {
      #pragma unroll
      for (int i=0;i<16;++i) sacc[stile][i] = 0.f;
      #pragma unroll
      for (int kc=0; kc<8; ++kc) {
        const int sl = stile*32 + l31;
        const int gc = kc*2 + hi;
        const int cl = (gc & 8) | ((gc ^ sl) & 7);
        s16x8 kf = *(const s16x8*)(Kl[cur] + sl*128 + cl*8);
        sacc[stile] = __builtin_amdgcn_mfma_f32_32x32x16_bf16(kf, qf[kc], sacc[stile], 0,0,0);
      }
    }

    float tm[8];
    #pragma unroll
    for (int i=0;i<8;++i)
      tm[i] = fmaxf(fmaxf(sacc[0][i], sacc[0][i+8]), fmaxf(sacc[1][i], sacc[1][i+8]));
    float pm = fmaxf(fmaxf(fmaxf(tm[0],tm[1]), fmaxf(tm[2],tm[3])),
                     fmaxf(fmaxf(tm[4],tm[5]), fmaxf(tm[6],tm[7])));
    pm = fmaxf(pm, __shfl_xor(pm, 32));

    if (__any(pm > m_run + 8.f)) {
      const float mnew = fmaxf(m_run, pm);
      const float alpha = __expf(m_run - mnew);
      m_run = mnew;
      l_run *= alpha;
      #pragma unroll
      for (int r=0;r<16;++r) {
        const int qr = (r&3) + 8*(r>>2) + 4*hi;
        const float ar = __shfl(alpha, qr);
        #pragma unroll
        for (int dt2=0;dt2<4;++dt2) oacc[dt2][r] *= ar;
      }
    }

    float ps = 0.f;
    #pragma unroll
    for (int stile=0; stile<2; ++stile)
      #pragma unroll
      for (int i=0;i<16;++i) {
        const float v = __expf(sacc[stile][i] - m_run);
        sacc[stile][i] = v;
        ps += v;
      }
    ps += __shfl_xor(ps, 32);
    l_run += ps;

    s16x8 pf[4];
    #pragma unroll
    for (int kc2=0; kc2<4; ++kc2) {
      const int stile = kc2 >> 1;
      const int rb = (kc2 & 1) * 8;
      const unsigned A = cvt_pk_bf16(sacc[stile][rb+0], sacc[stile][rb+1]);
      const unsigned B = cvt_pk_bf16(sacc[stile][rb+2], sacc[stile][rb+3]);
      const unsigned C = cvt_pk_bf16(sacc[stile][rb+4], sacc[stile][rb+5]);
      const unsigned D = cvt_pk_bf16(sacc[stile][rb+6], sacc[stile][rb+7]);
      const unsigned x1 = (unsigned)__shfl_xor((int)(hi ? A : C), 32);
      const unsigned x2 = (unsigned)__shfl_xor((int)(hi ? B : D), 32);
      union { unsigned u[4]; s16x8 v; } fr;
      fr.u[0] = hi ? x1 : A;
      fr.u[1] = hi ? x2 : B;
      fr.u[2] = hi ? C : x1;
      fr.u[3] = hi ? D : x2;
      pf[kc2] = fr.v;
    }

    #pragma unroll
    for (int dt2=0; dt2<4; ++dt2) {
      const int d = dt2*32 + l31;
      #pragma unroll
      for (int kc2=0; kc2<4; ++kc2) {
        const int g3 = kc2*2 + hi;
        const int cl3 = (g3 ^ d) & 7;
        s16x8 vf = *(const s16x8*)(Vl[cur] + d*64 + cl3*8);
        oacc[dt2] = __builtin_amdgcn_mfma_f32_32x32x16_bf16(pf[kc2], vf, oacc[dt2], 0,0,0);
      }
    }

    __syncthreads();
    cur ^= 1;
  }

  const float linv = 1.f / l_run;
  #pragma unroll
  for (int r=0;r<16;++r) {
    const int qr = (r&3) + 8*(r>>2) + 4*hi;
    const float lr = __shfl(linv, qr);
    const size_t row = (size_t)(b*1024 + q0 + qr)*1024 + colh;
    #pragma unroll
    for (int dt2=0;dt2<4;++dt2)
      O[row + dt2*32 + l31] = f2bf(oacc[dt2][r] * lr);
  }
}

// ---------------- LayerNorm (block per row of 1024) ----------------

__global__ __launch_bounds__(256) void ln_kernel(
    const float* __restrict__ y, const float* __restrict__ g, const float* __restrict__ bb,
    u16* __restrict__ out)
{
  const int row = blockIdx.x, t = threadIdx.x;
  float4 v = ((const float4*)y)[row*256 + t];
  float s  = v.x + v.y + v.z + v.w;
  float s2 = v.x*v.x + v.y*v.y + v.z*v.z + v.w*v.w;
  #pragma unroll
  for (int off=1; off<64; off<<=1) { s += __shfl_xor(s, off); s2 += __shfl_xor(s2, off); }
  __shared__ float ps[4], ps2[4];
  const int w = t >> 6;
  if ((t & 63) == 0) { ps[w] = s; ps2[w] = s2; }
  __syncthreads();
  s  = ps[0] + ps[1] + ps[2] + ps[3];
  s2 = ps2[0] + ps2[1] + ps2[2] + ps2[3];
  const float mu = s * (1.f/1024.f);
  const float var = s2 * (1.f/1024.f) - mu*mu;
  const float rs = rsqrtf(var + 1e-5f);
  float4 gg = ((const float4*)g)[t];
  float4 bv = ((const float4*)bb)[t];
  u16x4 o = { f2bf((v.x-mu)*rs*gg.x + bv.x),
              f2bf((v.y-mu)*rs*gg.y + bv.y),
              f2bf((v.z-mu)*rs*gg.z + bv.z),
              f2bf((v.w-mu)*rs*gg.w + bv.w) };
  ((u16x4*)out)[row*256 + t] = o;
}

// ---------------- launcher ----------------

extern "C" void kernel_launch(void* const* d_in, const int* in_sizes, int n_in,
                              void* d_out, int out_size, void* d_ws, size_t ws_size,
                              hipStream_t stream)
{
  (void)in_sizes; (void)n_in; (void)out_size; (void)ws_size;
  const float* x   = (const float*)d_in[0];
  const float* ht  = (const float*)d_in[1];
  const float* ha  = (const float*)d_in[2];
  const float* pp  = (const float*)d_in[3];
  const float* Wq  = (const float*)d_in[4];
  const float* bq  = (const float*)d_in[5];
  const float* Wk  = (const float*)d_in[6];
  const float* bk  = (const float*)d_in[7];
  const float* Wv  = (const float*)d_in[8];
  const float* bv  = (const float*)d_in[9];
  const float* Wo  = (const float*)d_in[10];
  const float* bo  = (const float*)d_in[11];
  const float* gat = (const float*)d_in[12];
  const float* lng = (const float*)d_in[13];
  const float* lnb = (const float*)d_in[14];
  const float* Wf  = (const float*)d_in[15];
  const float* bfp = (const float*)d_in[16];
  float* out = (float*)d_out;

  char* ws = (char*)d_ws;
  size_t off = 0;
  auto alloc = [&](size_t bytes) { void* r = ws + off; off += (bytes + 255) & ~255ull; return r; };
  u16* M    = (u16*)alloc(13312ull*1024*2);  // dead after QKV gemm; Vtg/Y overlay
  u16* Wqkv = (u16*)alloc(3072ull*1024*2);   // dead after QKV gemm
  u16* Wobf = (u16*)alloc(1024ull*1024*2);
  u16* Wfbf = (u16*)alloc(1024ull*1024*2);
  u16* Qb   = (u16*)alloc(8192ull*1024*2);   // dead after flash
  u16* Kb2  = (u16*)alloc(13312ull*1024*2);
  u16* Vb2  = (u16*)alloc(13312ull*1024*2);
  u16* Ab   = (u16*)alloc(8192ull*1024*2);
  u16* Vtg  = M;                             // V^T overlay on M
  float* Y  = (float*)M;                     // fp32 y overlays M+Wqkv after flash
  u16* Ln   = Qb;

  hipLaunchKernelGGL(cvt_weights, dim3(5120), dim3(256), 0, stream,
                     Wq, Wk, Wv, Wo, Wf, Wqkv, Wobf, Wfbf);
  hipLaunchKernelGGL(build_m, dim3(13312), dim3(256), 0, stream, x, ht, ha, pp, M);
  hipLaunchKernelGGL((gemm128<0>), dim3(2496), dim3(256), 0, stream,
                     M, Wqkv, bq, bk, bv, gat,
                     (void*)Qb, (void*)Kb2, (void*)Vb2, nullptr, 13, 4);
  hipLaunchKernelGGL(vtrans, dim3(26, 16, 8), dim3(256), 0, stream, Vb2, Vtg);
  hipLaunchKernelGGL(flash_attn, dim3(512), dim3(256), 0, stream, Qb, Kb2, Vtg, Ab);
  hipLaunchKernelGGL((gemm128<1>), dim3(512), dim3(256), 0, stream,
                     Ab, Wobf, bo, nullptr, nullptr, nullptr,
                     (void*)Y, nullptr, nullptr, x, 8, 8);
  hipLaunchKernelGGL(ln_kernel, dim3(8192), dim3(256), 0, stream, Y, lng, lnb, Ln);
  hipLaunchKernelGGL((gemm128<2>), dim3(512), dim3(256), 0, stream,
                     Ln, Wfbf, bfp, nullptr, nullptr, nullptr,
                     (void*)out, nullptr, nullptr, nullptr, 8, 8);
}

// Round 11
// 423.014 us; speedup vs baseline: 1.3788x; 1.3788x over previous
//
#include <hip/hip_runtime.h>
#include <hip/hip_bf16.h>
#include <math.h>

typedef unsigned short u16;
typedef __attribute__((ext_vector_type(8))) short s16x8;
typedef __attribute__((ext_vector_type(4))) float f32x4;
typedef __attribute__((ext_vector_type(16))) float f32x16;
typedef __attribute__((ext_vector_type(4))) unsigned short u16x4;

__device__ __forceinline__ u16 f2bf(float f) {
  union { float f; unsigned u; } v; v.f = f;
  unsigned r = (v.u + 0x7FFFu + ((v.u >> 16) & 1u)) >> 16;
  return (u16)r;
}

__device__ __forceinline__ void gload16(const void* g, void* l) {
  __builtin_amdgcn_global_load_lds((const __attribute__((address_space(1))) unsigned int*)g,
                                   (__attribute__((address_space(3))) unsigned int*)l, 16, 0, 0);
}

__device__ __forceinline__ unsigned cvt_pk_bf16(float a, float b) {
  unsigned r;
  asm("v_cvt_pk_bf16_f32 %0, %1, %2" : "=v"(r) : "v"(a), "v"(b));
  return r;
}

// ---------------- elementwise prep ----------------

__global__ __launch_bounds__(256) void cvt_weights(
    const float* __restrict__ wq, const float* __restrict__ wk, const float* __restrict__ wv,
    const float* __restrict__ wo, const float* __restrict__ wf,
    u16* __restrict__ wqkv, u16* __restrict__ wobf, u16* __restrict__ wfbf)
{
  int i = blockIdx.x * 256 + threadIdx.x;   // 5 * 262144 float4 units
  int which = i >> 18;
  int idx = i & 262143;
  const float* src = which==0 ? wq : which==1 ? wk : which==2 ? wv : which==3 ? wo : wf;
  float4 v = ((const float4*)src)[idx];
  u16x4 o = { f2bf(v.x), f2bf(v.y), f2bf(v.z), f2bf(v.w) };
  u16* dst = which < 3 ? (wqkv + (size_t)which*1048576) : (which==3 ? wobf : wfbf);
  ((u16x4*)dst)[idx] = o;
}

// M[b*1664 + s] = rows of [x(1024); h_a(64); p(64); h_t(512)] per batch, bf16
__global__ __launch_bounds__(256) void build_m(
    const float* __restrict__ x, const float* __restrict__ ht,
    const float* __restrict__ ha, const float* __restrict__ p,
    u16* __restrict__ M)
{
  int row = blockIdx.x; int t = threadIdx.x;
  int b = row / 1664, s = row % 1664;
  const float* src;
  if (s < 1024)      src = x  + (size_t)(b*1024 + s)*1024;
  else if (s < 1088) src = ha + (size_t)(b*64 + (s-1024))*1024;
  else if (s < 1152) src = p  + (size_t)(b*64 + (s-1088))*1024;
  else               src = ht + (size_t)(b*512 + (s-1152))*1024;
  float4 v = ((const float4*)src)[t];
  u16x4 o = { f2bf(v.x), f2bf(v.y), f2bf(v.z), f2bf(v.w) };
  ((u16x4*)(M + (size_t)row*1024))[t] = o;
}

// ---------------- unified 128x128 GEMM, K=1024, BK=32, TRIPLE-buffered ----------------
// Round-7-proven structure: 48 KB LDS -> 3 blocks/CU ((256,3)), depth-2 prefetch,
// counted vmcnt(4) per iter (never 0 until tail). L2 working set/XCD ~4.9 MB.
// EPI 0: fused QKV epilogue. EPI 1: +bias+resid -> fp32. EPI 2: +bias+relu -> fp32.

template<int EPI>
__global__ __launch_bounds__(256, 3) void gemm128(
    const u16* __restrict__ A, const u16* __restrict__ Bw,
    const float* __restrict__ bias0, const float* __restrict__ bias1,
    const float* __restrict__ bias2, const float* __restrict__ gat,
    void* o0, void* o1, void* o2, const float* __restrict__ resid,
    int mpx, int ng)
{
  __shared__ __align__(16) u16 As3[3][128*32];   // 8 KB per buf per matrix
  __shared__ __align__(16) u16 Bs3[3][128*32];   // total 48 KB -> 3 blocks/CU

  const int tid = threadIdx.x;
  const int l = tid & 63;
  const int w = tid >> 6;            // 0..3
  const int wr = w >> 1, wc = w & 1; // 2x2 wave grid, 64x64 per wave
  const int l15 = l & 15, lg = l >> 4;

  // XCD-chunked swizzle: each XCD owns mpx contiguous mt x nt-groups of ng.
  const int b0 = blockIdx.x;
  const int xcd = b0 & 7;
  const int loc = b0 >> 3;
  const int chunk = mpx * ng;
  const int g = loc / chunk, r5 = loc % chunk;
  const int mt = xcd*mpx + (r5 % mpx);
  const int nt = g*ng + (r5 / mpx);
  const int m0 = mt * 128, n0 = nt * 128;

  if constexpr (EPI == 0) {
    if (n0 < 1024 && (m0 % 1664) >= 1024) return;  // Q-only tile, all non-token rows
  }

  // stage K-tile kt into buffer sb; chunk-XOR c^=(r>>1)&3 via pre-swizzled global src.
  auto stage = [&](int kt, int sb) {
    #pragma unroll
    for (int i=0;i<2;++i) {
      const int e = i*256 + tid;
      const int rr = e >> 2, c2 = e & 3;
      const int gch = c2 ^ ((rr >> 1) & 3);
      gload16(A + (size_t)(m0 + rr)*1024 + kt*32 + gch*8,
              (void*)(As3[sb] + (i*256 + w*64)*8));
    }
    #pragma unroll
    for (int i=0;i<2;++i) {
      const int e = i*256 + tid;
      const int rr = e >> 2, c2 = e & 3;
      const int gch = c2 ^ ((rr >> 1) & 3);
      gload16(Bw + (size_t)(n0 + rr)*1024 + kt*32 + gch*8,
              (void*)(Bs3[sb] + (i*256 + w*64)*8));
    }
  };

  f32x4 acc[4][4];
  #pragma unroll
  for (int i=0;i<4;++i)
    #pragma unroll
    for (int j=0;j<4;++j) acc[i][j] = (f32x4){0,0,0,0};

  // prologue: tiles 0,1 staged; wait tile0 (retire oldest 4 of 8)
  stage(0, 0); stage(1, 1);
  asm volatile("s_waitcnt vmcnt(4)\ns_barrier" ::: "memory");

  int cur = 0;
  for (int t = 0; t < 32; ++t) {
    const int sb = cur >= 1 ? cur - 1 : 2;   // buffer freed at t-1
    if (t + 2 < 32) stage(t + 2, sb);

    s16x8 af[4], bf[4];
    #pragma unroll
    for (int mi=0;mi<4;++mi) {
      const int rr = wr*64 + mi*16 + l15;
      af[mi] = *(const s16x8*)(As3[cur] + rr*32 + ((lg ^ ((rr>>1)&3))<<3));
    }
    #pragma unroll
    for (int ni=0;ni<4;++ni) {
      const int rr = wc*64 + ni*16 + l15;
      bf[ni] = *(const s16x8*)(Bs3[cur] + rr*32 + ((lg ^ ((rr>>1)&3))<<3));
    }

    __builtin_amdgcn_s_setprio(1);
    #pragma unroll
    for (int mi=0;mi<4;++mi)
      #pragma unroll
      for (int ni=0;ni<4;++ni)
        acc[mi][ni] = __builtin_amdgcn_mfma_f32_16x16x32_bf16(af[mi], bf[ni], acc[mi][ni], 0,0,0);
    __builtin_amdgcn_s_setprio(0);

    if (t < 30)       asm volatile("s_waitcnt vmcnt(4)\ns_barrier" ::: "memory");
    else if (t == 30) asm volatile("s_waitcnt vmcnt(0)\ns_barrier" ::: "memory");
    cur = cur == 2 ? 0 : cur + 1;
  }

  // epilogue
  float ratio = 0.f;
  if constexpr (EPI == 0) ratio = tanhf(gat[0]);

  #pragma unroll
  for (int mi=0;mi<4;++mi) {
    #pragma unroll
    for (int ni=0;ni<4;++ni) {
      #pragma unroll
      for (int rr=0;rr<4;++rr) {
        const int row = m0 + wr*64 + mi*16 + lg*4 + rr;
        const int col = n0 + wc*64 + ni*16 + l15;
        const float a = acc[mi][ni][rr];
        if constexpr (EPI == 0) {
          const int b = row / 1664, s = row % 1664;
          if (col < 1024) {
            if (s < 1024) {
              float v = a + bias0[col];
              ((u16*)o0)[(size_t)(b*1024 + s)*1024 + col] = f2bf(v * 0.08838834764831845f);
            }
          } else if (col < 2048) {
            float v = a + bias1[col-1024];
            if (s >= 1152) v *= ratio;
            ((u16*)o1)[(size_t)row*1024 + (col-1024)] = f2bf(v);
          } else {
            float v = a + bias2[col-2048];
            ((u16*)o2)[(size_t)row*1024 + (col-2048)] = f2bf(v);
          }
        } else if constexpr (EPI == 1) {
          float v = a + bias0[col] + resid[(size_t)row*1024 + col];
          ((float*)o0)[(size_t)row*1024 + col] = v;
        } else {
          float v = a + bias0[col];
          ((float*)o0)[(size_t)row*1024 + col] = fmaxf(v, 0.f);
        }
      }
    }
  }
}

// ---------------- V transpose: Vt[b][c=1024][s=1664] = V[b][s][c] ----------------

__global__ __launch_bounds__(256) void vtrans(
    const u16* __restrict__ V, u16* __restrict__ Vt)
{
  __shared__ u16 Ls[64][68];
  const int st = blockIdx.x, dt = blockIdx.y, b = blockIdx.z;
  const int t = threadIdx.x;
  const int rq = t >> 4, c4 = t & 15;
  #pragma unroll
  for (int i=0;i<4;++i) {
    const int r = i*16 + rq;
    u16x4 v = *(const u16x4*)(V + ((size_t)(b*1664 + st*64 + r))*1024 + dt*64 + c4*4);
    Ls[r][c4*4+0] = v[0]; Ls[r][c4*4+1] = v[1]; Ls[r][c4*4+2] = v[2]; Ls[r][c4*4+3] = v[3];
  }
  __syncthreads();
  #pragma unroll
  for (int i=0;i<4;++i) {
    const int dr = i*16 + rq;
    u16x4 ov = { Ls[c4*4+0][dr], Ls[c4*4+1][dr], Ls[c4*4+2][dr], Ls[c4*4+3][dr] };
    *(u16x4*)(Vt + ((size_t)(b*1024 + dt*64 + dr))*1664 + st*64 + c4*4) = ov;
  }
}

// ---------------- flash attention, 32x32 swapped-QK, S=1664, D=128 ----------------

__global__ __launch_bounds__(256, 2) void flash_attn(
    const u16* __restrict__ Q, const u16* __restrict__ Kb, const u16* __restrict__ Vtg,
    u16* __restrict__ O)
{
  __shared__ __align__(16) u16 Kl[2][64*128];   // [s][16 chunks], chunk low3 ^= s&7
  __shared__ __align__(16) u16 Vl[2][128*64];   // [d][8 chunks], chunk ^= d&7

  const int tid = threadIdx.x;
  const int l = tid & 63;
  const int w = tid >> 6;
  const int l31 = l & 31;
  const int hi = l >> 5;
  const int bh = blockIdx.x & 63;
  const int qt = blockIdx.x >> 6;
  const int b = bh >> 3, h = bh & 7;
  const int colh = h * 128;
  const int q0 = qt*128 + w*32;

  s16x8 qf[8];
  {
    const size_t qrow = (size_t)(b*1024 + q0 + l31)*1024 + colh;
    #pragma unroll
    for (int kc=0;kc<8;++kc)
      qf[kc] = *(const s16x8*)(Q + qrow + kc*16 + hi*8);
  }

  f32x16 oacc[4];
  #pragma unroll
  for (int dt2=0;dt2<4;++dt2)
    #pragma unroll
    for (int i=0;i<16;++i) oacc[dt2][i] = 0.f;
  float m_run = -INFINITY, l_run = 0.f;

  const size_t kbase  = (size_t)(b*1664)*1024 + colh;
  const size_t vtbase = (size_t)(b*1024 + colh)*1664;

  auto stage = [&](int st, int nb) {
    const int s0 = st*64;
    #pragma unroll
    for (int i=0;i<4;++i) {
      const int e = i*256 + tid;
      const int sl = e >> 4, c = e & 15;
      const int g = (c & 8) | ((c ^ sl) & 7);
      gload16(Kb + kbase + (size_t)(s0 + sl)*1024 + g*8,
              (void*)(Kl[nb] + (i*256 + w*64)*8));
    }
    #pragma unroll
    for (int i=0;i<4;++i) {
      const int e = i*256 + tid;
      const int d = e >> 3, c3 = e & 7;
      const int g3 = (c3 ^ d) & 7;
      gload16(Vtg + vtbase + (size_t)d*1664 + s0 + g3*8,
              (void*)(Vl[nb] + (i*256 + w*64)*8));
    }
  };

  stage(0, 0);
  __syncthreads();
  int cur = 0;

  for (int st=0; st<26; ++st) {
    if (st + 1 < 26) stage(st + 1, cur ^ 1);

    f32x16 sacc[2];
    #pragma unroll
    for (int stile=0; stile<2; ++stile) {
      #pragma unroll
      for (int i=0;i<16;++i) sacc[stile][i] = 0.f;
      #pragma unroll
      for (int kc=0; kc<8; ++kc) {
        const int sl = stile*32 + l31;
        const int gc = kc*2 + hi;
        const int cl = (gc & 8) | ((gc ^ sl) & 7);
        s16x8 kf = *(const s16x8*)(Kl[cur] + sl*128 + cl*8);
        sacc[stile] = __builtin_amdgcn_mfma_f32_32x32x16_bf16(kf, qf[kc], sacc[stile], 0,0,0);
      }
    }

    float tm[8];
    #pragma unroll
    for (int i=0;i<8;++i)
      tm[i] = fmaxf(fmaxf(sacc[0][i], sacc[0][i+8]), fmaxf(sacc[1][i], sacc[1][i+8]));
    float pm = fmaxf(fmaxf(fmaxf(tm[0],tm[1]), fmaxf(tm[2],tm[3])),
                     fmaxf(fmaxf(tm[4],tm[5]), fmaxf(tm[6],tm[7])));
    pm = fmaxf(pm, __shfl_xor(pm, 32));

    if (__any(pm > m_run + 8.f)) {
      const float mnew = fmaxf(m_run, pm);
      const float alpha = __expf(m_run - mnew);
      m_run = mnew;
      l_run *= alpha;
      #pragma unroll
      for (int r=0;r<16;++r) {
        const int qr = (r&3) + 8*(r>>2) + 4*hi;
        const float ar = __shfl(alpha, qr);
        #pragma unroll
        for (int dt2=0;dt2<4;++dt2) oacc[dt2][r] *= ar;
      }
    }

    float ps = 0.f;
    #pragma unroll
    for (int stile=0; stile<2; ++stile)
      #pragma unroll
      for (int i=0;i<16;++i) {
        const float v = __expf(sacc[stile][i] - m_run);
        sacc[stile][i] = v;
        ps += v;
      }
    ps += __shfl_xor(ps, 32);
    l_run += ps;

    s16x8 pf[4];
    #pragma unroll
    for (int kc2=0; kc2<4; ++kc2) {
      const int stile = kc2 >> 1;
      const int rb = (kc2 & 1) * 8;
      const unsigned A = cvt_pk_bf16(sacc[stile][rb+0], sacc[stile][rb+1]);
      const unsigned B = cvt_pk_bf16(sacc[stile][rb+2], sacc[stile][rb+3]);
      const unsigned C = cvt_pk_bf16(sacc[stile][rb+4], sacc[stile][rb+5]);
      const unsigned D = cvt_pk_bf16(sacc[stile][rb+6], sacc[stile][rb+7]);
      const unsigned x1 = (unsigned)__shfl_xor((int)(hi ? A : C), 32);
      const unsigned x2 = (unsigned)__shfl_xor((int)(hi ? B : D), 32);
      union { unsigned u[4]; s16x8 v; } fr;
      fr.u[0] = hi ? x1 : A;
      fr.u[1] = hi ? x2 : B;
      fr.u[2] = hi ? C : x1;
      fr.u[3] = hi ? D : x2;
      pf[kc2] = fr.v;
    }

    #pragma unroll
    for (int dt2=0; dt2<4; ++dt2) {
      const int d = dt2*32 + l31;
      #pragma unroll
      for (int kc2=0; kc2<4; ++kc2) {
        const int g3 = kc2*2 + hi;
        const int cl3 = (g3 ^ d) & 7;
        s16x8 vf = *(const s16x8*)(Vl[cur] + d*64 + cl3*8);
        oacc[dt2] = __builtin_amdgcn_mfma_f32_32x32x16_bf16(pf[kc2], vf, oacc[dt2], 0,0,0);
      }
    }

    __syncthreads();
    cur ^= 1;
  }

  const float linv = 1.f / l_run;
  #pragma unroll
  for (int r=0;r<16;++r) {
    const int qr = (r&3) + 8*(r>>2) + 4*hi;
    const float lr = __shfl(linv, qr);
    const size_t row = (size_t)(b*1024 + q0 + qr)*1024 + colh;
    #pragma unroll
    for (int dt2=0;dt2<4;++dt2)
      O[row + dt2*32 + l31] = f2bf(oacc[dt2][r] * lr);
  }
}

// ---------------- LayerNorm (block per row of 1024) ----------------

__global__ __launch_bounds__(256) void ln_kernel(
    const float* __restrict__ y, const float* __restrict__ g, const float* __restrict__ bb,
    u16* __restrict__ out)
{
  const int row = blockIdx.x, t = threadIdx.x;
  float4 v = ((const float4*)y)[row*256 + t];
  float s  = v.x + v.y + v.z + v.w;
  float s2 = v.x*v.x + v.y*v.y + v.z*v.z + v.w*v.w;
  #pragma unroll
  for (int off=1; off<64; off<<=1) { s += __shfl_xor(s, off); s2 += __shfl_xor(s2, off); }
  __shared__ float ps[4], ps2[4];
  const int w = t >> 6;
  if ((t & 63) == 0) { ps[w] = s; ps2[w] = s2; }
  __syncthreads();
  s  = ps[0] + ps[1] + ps[2] + ps[3];
  s2 = ps2[0] + ps2[1] + ps2[2] + ps2[3];
  const float mu = s * (1.f/1024.f);
  const float var = s2 * (1.f/1024.f) - mu*mu;
  const float rs = rsqrtf(var + 1e-5f);
  float4 gg = ((const float4*)g)[t];
  float4 bv = ((const float4*)bb)[t];
  u16x4 o = { f2bf((v.x-mu)*rs*gg.x + bv.x),
              f2bf((v.y-mu)*rs*gg.y + bv.y),
              f2bf((v.z-mu)*rs*gg.z + bv.z),
              f2bf((v.w-mu)*rs*gg.w + bv.w) };
  ((u16x4*)out)[row*256 + t] = o;
}

// ---------------- launcher ----------------

extern "C" void kernel_launch(void* const* d_in, const int* in_sizes, int n_in,
                              void* d_out, int out_size, void* d_ws, size_t ws_size,
                              hipStream_t stream)
{
  (void)in_sizes; (void)n_in; (void)out_size; (void)ws_size;
  const float* x   = (const float*)d_in[0];
  const float* ht  = (const float*)d_in[1];
  const float* ha  = (const float*)d_in[2];
  const float* pp  = (const float*)d_in[3];
  const float* Wq  = (const float*)d_in[4];
  const float* bq  = (const float*)d_in[5];
  const float* Wk  = (const float*)d_in[6];
  const float* bk  = (const float*)d_in[7];
  const float* Wv  = (const float*)d_in[8];
  const float* bv  = (const float*)d_in[9];
  const float* Wo  = (const float*)d_in[10];
  const float* bo  = (const float*)d_in[11];
  const float* gat = (const float*)d_in[12];
  const float* lng = (const float*)d_in[13];
  const float* lnb = (const float*)d_in[14];
  const float* Wf  = (const float*)d_in[15];
  const float* bfp = (const float*)d_in[16];
  float* out = (float*)d_out;

  char* ws = (char*)d_ws;
  size_t off = 0;
  auto alloc = [&](size_t bytes) { void* r = ws + off; off += (bytes + 255) & ~255ull; return r; };
  u16* M    = (u16*)alloc(13312ull*1024*2);  // dead after QKV gemm; Vtg/Y overlay
  u16* Wqkv = (u16*)alloc(3072ull*1024*2);   // dead after QKV gemm
  u16* Wobf = (u16*)alloc(1024ull*1024*2);
  u16* Wfbf = (u16*)alloc(1024ull*1024*2);
  u16* Qb   = (u16*)alloc(8192ull*1024*2);   // dead after flash
  u16* Kb2  = (u16*)alloc(13312ull*1024*2);
  u16* Vb2  = (u16*)alloc(13312ull*1024*2);
  u16* Ab   = (u16*)alloc(8192ull*1024*2);
  u16* Vtg  = M;                             // V^T overlay on M
  float* Y  = (float*)M;                     // fp32 y overlays M+Wqkv after flash
  u16* Ln   = Qb;

  hipLaunchKernelGGL(cvt_weights, dim3(5120), dim3(256), 0, stream,
                     Wq, Wk, Wv, Wo, Wf, Wqkv, Wobf, Wfbf);
  hipLaunchKernelGGL(build_m, dim3(13312), dim3(256), 0, stream, x, ht, ha, pp, M);
  hipLaunchKernelGGL((gemm128<0>), dim3(2496), dim3(256), 0, stream,
                     M, Wqkv, bq, bk, bv, gat,
                     (void*)Qb, (void*)Kb2, (void*)Vb2, nullptr, 13, 4);
  hipLaunchKernelGGL(vtrans, dim3(26, 16, 8), dim3(256), 0, stream, Vb2, Vtg);
  hipLaunchKernelGGL(flash_attn, dim3(512), dim3(256), 0, stream, Qb, Kb2, Vtg, Ab);
  hipLaunchKernelGGL((gemm128<1>), dim3(512), dim3(256), 0, stream,
                     Ab, Wobf, bo, nullptr, nullptr, nullptr,
                     (void*)Y, nullptr, nullptr, x, 8, 8);
  hipLaunchKernelGGL(ln_kernel, dim3(8192), dim3(256), 0, stream, Y, lng, lnb, Ln);
  hipLaunchKernelGGL((gemm128<2>), dim3(512), dim3(256), 0, stream,
                     Ln, Wfbf, bfp, nullptr, nullptr, nullptr,
                     (void*)out, nullptr, nullptr, nullptr, 8, 8);
}